// Round 7
// baseline (480.884 us; speedup 1.0000x reference)
//
#include <hip/hip_runtime.h>
#include <math.h>

#define NN 50000
#define NE 800000
#define IND 256
#define ED 64
#define EMB 128
#define NH 8
#define HD 16
#define ECH 200000                      // edge chunk (4 chunks)

typedef short bf16x8 __attribute__((ext_vector_type(8)));
typedef float f32x4 __attribute__((ext_vector_type(4)));

#define NPROJ ((NN + 31) / 32)
#define NHIST ((NE + 255) / 256)

__device__ __forceinline__ unsigned short rne16(float f) {
    unsigned u = __float_as_uint(f);
    unsigned r = u + 0x7FFFu + ((u >> 16) & 1u);
    return (unsigned short)(r >> 16);
}

__device__ __forceinline__ float bf2f(short s) {
    return __uint_as_float(((unsigned)(unsigned short)s) << 16);
}

__device__ __forceinline__ float mishf(float v) {
    float t = __expf(fminf(v, 20.f));
    float u = 1.f + t;
    u = u * u;
    return v * (u - 1.f) * __builtin_amdgcn_rcpf(u + 1.f);
}

// ------- fused: node projection (blocks < NPROJ) + rcv histogram -----------
__global__ __launch_bounds__(256) void k_proj_hist(
    const float* __restrict__ X, const float* __restrict__ W,
    const float* __restrict__ b, float* __restrict__ hout,
    short* __restrict__ hbf, const int* __restrict__ rcv,
    int* __restrict__ cnt) {
    if (blockIdx.x >= NPROJ) {
        int e = (blockIdx.x - NPROJ) * 256 + threadIdx.x;
        if (e < NE) atomicAdd(&cnt[rcv[e]], 1);
        return;
    }
    __shared__ float As[32][32];
    __shared__ float Ws[32][128];
    const int row0 = blockIdx.x * 32;
    const int tid = threadIdx.x;
    const int col = (tid & 31) * 4;
    const int rb  = (tid >> 5) * 4;
    float acc[4][4] = {};
    for (int k0 = 0; k0 < IND; k0 += 32) {
        {
            int r = tid >> 5, kk = tid & 31;
            #pragma unroll
            for (int i = 0; i < 4; ++i) {
                int rr = r + i * 8;
                int gr = row0 + rr;
                As[rr][kk] = (gr < NN) ? X[(size_t)gr * IND + k0 + kk] : 0.f;
            }
        }
        {
            int j = tid & 127, kb = tid >> 7;
            #pragma unroll
            for (int i = 0; i < 16; ++i) {
                int kk = kb + i * 2;
                Ws[kk][j] = W[(size_t)(k0 + kk) * EMB + j];
            }
        }
        __syncthreads();
        #pragma unroll
        for (int kk = 0; kk < 32; ++kk) {
            float4 wv = *(const float4*)&Ws[kk][col];
            float av[4];
            #pragma unroll
            for (int r = 0; r < 4; ++r) av[r] = As[rb + r][kk];
            #pragma unroll
            for (int r = 0; r < 4; ++r) {
                acc[r][0] = fmaf(av[r], wv.x, acc[r][0]);
                acc[r][1] = fmaf(av[r], wv.y, acc[r][1]);
                acc[r][2] = fmaf(av[r], wv.z, acc[r][2]);
                acc[r][3] = fmaf(av[r], wv.w, acc[r][3]);
            }
        }
        __syncthreads();
    }
    #pragma unroll
    for (int r = 0; r < 4; ++r) {
        int gr = row0 + rb + r;
        if (gr < NN) {
            float4 o;
            o.x = acc[r][0] + b[col];
            o.y = acc[r][1] + b[col + 1];
            o.z = acc[r][2] + b[col + 2];
            o.w = acc[r][3] + b[col + 3];
            *(float4*)&hout[(size_t)gr * EMB + col] = o;
            short4 hb;
            hb.x = (short)rne16(o.x);
            hb.y = (short)rne16(o.y);
            hb.z = (short)rne16(o.z);
            hb.w = (short)rne16(o.w);
            *(short4*)&hbf[(size_t)gr * EMB + col] = hb;
        }
    }
}

// ---------------- CSR build ------------------------------------------------
__global__ __launch_bounds__(512) void k_part(const int* __restrict__ cnt,
                                              int* __restrict__ rowptr,
                                              int* __restrict__ part) {
    __shared__ int sm[512];
    const int t = threadIdx.x;
    const int idx = blockIdx.x * 512 + t;
    int v = (idx < NN) ? cnt[idx] : 0;
    sm[t] = v;
    __syncthreads();
    #pragma unroll
    for (int off = 1; off < 512; off <<= 1) {
        int y = (t >= off) ? sm[t - off] : 0;
        __syncthreads();
        sm[t] += y;
        __syncthreads();
    }
    if (idx < NN) rowptr[idx] = sm[t] - v;
    if (t == 511) part[blockIdx.x] = sm[511];
}

__global__ __launch_bounds__(128) void k_scan2(const int* __restrict__ part,
                                               int* __restrict__ partoff,
                                               int* __restrict__ rowptr) {
    __shared__ int sm[128];
    const int t = threadIdx.x;
    const int NB = (NN + 511) / 512;
    int v = (t < NB) ? part[t] : 0;
    sm[t] = v;
    __syncthreads();
    #pragma unroll
    for (int off = 1; off < 128; off <<= 1) {
        int y = (t >= off) ? sm[t - off] : 0;
        __syncthreads();
        sm[t] += y;
        __syncthreads();
    }
    if (t < NB) partoff[t] = sm[t] - v;
    if (t == 0) rowptr[NN] = NE;
}

__global__ __launch_bounds__(512) void k_fix(int* __restrict__ rowptr,
                                             const int* __restrict__ partoff,
                                             int* __restrict__ cursor) {
    const int idx = blockIdx.x * 512 + threadIdx.x;
    if (idx < NN) {
        int r = rowptr[idx] + partoff[blockIdx.x];
        rowptr[idx] = r;
        cursor[idx] = r;
    }
}

__global__ __launch_bounds__(256) void k_bucket(
    const int* __restrict__ snd, const int* __restrict__ rcv,
    int* __restrict__ cursor, int* __restrict__ csr_snd,
    int* __restrict__ csr_pos) {
    int e = blockIdx.x * 256 + threadIdx.x;
    if (e < NE) {
        int pos = atomicAdd(&cursor[rcv[e]], 1);
        csr_snd[pos] = snd[e];
        csr_pos[e] = pos;
    }
}

// ---------- edge projection GEMM (chunked): eproj = EFchunk @ We -> bf16 ---
// Wave = 16 edges. Column permutation in B staging (colg = lanecol*8+c)
// makes lane's 8 acc channels consecutive cols -> row-major bf16 output.
__global__ __launch_bounds__(256) void k_eproj(
    const float* __restrict__ EFc, const float* __restrict__ We,
    short* __restrict__ eproj, int nedge) {
    __shared__ bf16x8 BH[1024];
    __shared__ bf16x8 BL[1024];
    for (int t = threadIdx.x; t < 1024; t += 256) {
        int ckk = t >> 6;
        int lane = t & 63;
        int c = ckk >> 1;
        int colg = (lane & 15) * 8 + c;
        int kb = (ckk & 1) * 32 + (lane >> 4) * 8;
        bf16x8 vh, vl;
        #pragma unroll
        for (int j = 0; j < 8; ++j) {
            float f = We[(size_t)(kb + j) * EMB + colg];
            unsigned short hb = rne16(f);
            float fh = __uint_as_float((unsigned)hb << 16);
            vh[j] = (short)hb;
            vl[j] = (short)rne16(f - fh);
        }
        BH[t] = vh;
        BL[t] = vl;
    }
    __syncthreads();

    const int l = threadIdx.x & 63;
    const int lanecol = l & 15;
    const int q = l >> 4;
    const int wid = (blockIdx.x << 2) + (threadIdx.x >> 6);
    const int nW = gridDim.x << 2;
    const int NT = nedge / 16;

    for (int tIdx = wid; tIdx < NT; tIdx += nW) {
        const int e0 = tIdx * 16;
        const float* ar = EFc + (size_t)(e0 + lanecol) * ED + q * 8;
        float fa[16];
        *(float4*)&fa[0]  = *(const float4*)ar;
        *(float4*)&fa[4]  = *(const float4*)(ar + 4);
        *(float4*)&fa[8]  = *(const float4*)(ar + 32);
        *(float4*)&fa[12] = *(const float4*)(ar + 36);
        bf16x8 ahi[2], alo[2];
        #pragma unroll
        for (int kk = 0; kk < 2; ++kk) {
            #pragma unroll
            for (int j = 0; j < 8; ++j) {
                float f = fa[kk * 8 + j];
                unsigned short hb = rne16(f);
                float fh = __uint_as_float((unsigned)hb << 16);
                ahi[kk][j] = (short)hb;
                alo[kk][j] = (short)rne16(f - fh);
            }
        }
        f32x4 acc[8];
        #pragma unroll
        for (int c = 0; c < 8; ++c) acc[c] = (f32x4){0.f, 0.f, 0.f, 0.f};
        #pragma unroll
        for (int c = 0; c < 8; ++c) {
            #pragma unroll
            for (int kk = 0; kk < 2; ++kk) {
                bf16x8 bh = BH[(c * 2 + kk) * 64 + l];
                bf16x8 bl = BL[(c * 2 + kk) * 64 + l];
                acc[c] = __builtin_amdgcn_mfma_f32_16x16x32_bf16(ahi[kk], bh, acc[c], 0, 0, 0);
                acc[c] = __builtin_amdgcn_mfma_f32_16x16x32_bf16(alo[kk], bh, acc[c], 0, 0, 0);
                acc[c] = __builtin_amdgcn_mfma_f32_16x16x32_bf16(ahi[kk], bl, acc[c], 0, 0, 0);
            }
        }
        #pragma unroll
        for (int r = 0; r < 4; ++r) {
            const int e = e0 + (q << 2) + r;
            bf16x8 ov;
            #pragma unroll
            for (int c = 0; c < 8; ++c) ov[c] = (short)rne16(acc[c][r]);
            *(bf16x8*)(eproj + (size_t)e * EMB + lanecol * 8) = ov;
        }
    }
}

// ---------- logits: lean gather kernel, 1 edge per 16-lane group -----------
__global__ __launch_bounds__(256) void k_logit(
    const short* __restrict__ eproj, const float* __restrict__ Web,
    const float* __restrict__ Av, const short* __restrict__ hbf,
    const int* __restrict__ snd, const int* __restrict__ rcv,
    const int* __restrict__ csr_pos, float* __restrict__ ex_csr,
    int e0g, int nedge) {
    const int l = threadIdx.x & 63;
    const int lanecol = l & 15;
    const int q = l >> 4;
    const int wid = (blockIdx.x << 2) + (threadIdx.x >> 6);
    const int nW = gridDim.x << 2;

    float4 wbv0 = *(const float4*)&Web[lanecol * 8];
    float4 wbv1 = *(const float4*)&Web[lanecol * 8 + 4];
    float4 avv0 = *(const float4*)&Av[lanecol * 8];
    float4 avv1 = *(const float4*)&Av[lanecol * 8 + 4];
    float web[8] = {wbv0.x, wbv0.y, wbv0.z, wbv0.w, wbv1.x, wbv1.y, wbv1.z, wbv1.w};
    float av[8]  = {avv0.x, avv0.y, avv0.z, avv0.w, avv1.x, avv1.y, avv1.z, avv1.w};

    const int NG = nedge / 4;           // 4 edges per wave
    for (int g = wid; g < NG; g += nW) {
        const int e = g * 4 + q;        // chunk-local edge
        const int ge = e0g + e;         // global edge
        const int s = snd[ge], rn = rcv[ge], pos = csr_pos[ge];
        bf16x8 ep = *(const bf16x8*)(eproj + (size_t)e * EMB + lanecol * 8);
        bf16x8 hs = *(const bf16x8*)(hbf + (size_t)s * EMB + lanecol * 8);
        bf16x8 hr = *(const bf16x8*)(hbf + (size_t)rn * EMB + lanecol * 8);
        float pp = 0.f;
        #pragma unroll
        for (int c = 0; c < 8; ++c) {
            float v = bf2f(ep[c]) + web[c] + bf2f(hs[c]) + bf2f(hr[c]);
            pp = fmaf(mishf(v), av[c], pp);
        }
        pp += __shfl_xor(pp, 1, 16);
        if ((lanecol & 1) == 0) {
            ex_csr[(size_t)pos * NH + (lanecol >> 1)] = __expf(pp);
        }
    }
}

// --------- segmented aggregation: 4-wide chunked gathers -------------------
__global__ __launch_bounds__(256) void k_agg(
    const float* __restrict__ hbuf, const int* __restrict__ csr_snd,
    const float* __restrict__ ex_csr, const int* __restrict__ rowptr,
    float* __restrict__ out) {
    const int l = threadIdx.x & 63;
    const int node = blockIdx.x * 4 + (threadIdx.x >> 6);
    if (node >= NN) return;
    const int beg = rowptr[node], end = rowptr[node + 1];
    const int h0 = l >> 4, h1 = 4 + (l >> 4);
    float acc0 = 0.f, acc1 = 0.f, den0 = 0.f, den1 = 0.f;
    int j = beg;
    for (; j + 4 <= end; j += 4) {
        int s[4];
        float ex0[4], ex1[4], hs0[4], hs1[4];
        #pragma unroll
        for (int i = 0; i < 4; ++i) s[i] = csr_snd[j + i];
        #pragma unroll
        for (int i = 0; i < 4; ++i) {
            ex0[i] = ex_csr[(size_t)(j + i) * NH + h0];
            ex1[i] = ex_csr[(size_t)(j + i) * NH + h1];
        }
        #pragma unroll
        for (int i = 0; i < 4; ++i) {
            const float* hp = hbuf + (size_t)s[i] * EMB;
            hs0[i] = hp[l];
            hs1[i] = hp[l + 64];
        }
        #pragma unroll
        for (int i = 0; i < 4; ++i) {
            acc0 = fmaf(ex0[i], hs0[i], acc0);
            acc1 = fmaf(ex1[i], hs1[i], acc1);
            den0 += ex0[i];
            den1 += ex1[i];
        }
    }
    for (; j < end; ++j) {
        float ex0 = ex_csr[(size_t)j * NH + h0];
        float ex1 = ex_csr[(size_t)j * NH + h1];
        const float* hp = hbuf + (size_t)csr_snd[j] * EMB;
        acc0 = fmaf(ex0, hp[l], acc0);
        acc1 = fmaf(ex1, hp[l + 64], acc1);
        den0 += ex0;
        den1 += ex1;
    }
    float o0 = (end > beg) ? acc0 / den0 : 0.f;
    float o1 = (end > beg) ? acc1 / den1 : 0.f;
    out[(size_t)node * EMB + l] = o0;
    out[(size_t)node * EMB + l + 64] = o1;
}

extern "C" void kernel_launch(void* const* d_in, const int* in_sizes, int n_in,
                              void* d_out, int out_size, void* d_ws, size_t ws_size,
                              hipStream_t stream) {
    const float* X   = (const float*)d_in[0];
    const float* EF  = (const float*)d_in[1];
    const float* W   = (const float*)d_in[2];
    const float* Wb  = (const float*)d_in[3];
    const float* We  = (const float*)d_in[4];
    const float* Web = (const float*)d_in[5];
    const float* Av  = (const float*)d_in[6];
    const int* snd   = (const int*)d_in[7];
    const int* rcv   = (const int*)d_in[8];
    float* out = (float*)d_out;

    char* ws = (char*)d_ws;
    size_t off = 0;
    float* hbuf   = (float*)(ws + off); off += (size_t)NN * EMB * 4;   // 25.6 MB
    float* ex_csr = (float*)(ws + off); off += (size_t)NE * NH * 4;    // 25.6 MB
    int* csr_snd  = (int*)(ws + off);   off += (size_t)NE * 4;         // 3.2 MB
    int* csr_pos  = (int*)(ws + off);   off += (size_t)NE * 4;         // 3.2 MB
    int* rowptr   = (int*)(ws + off);   off += (size_t)(NN + 1) * 4;
    int* cursor   = (int*)(ws + off);   off += (size_t)NN * 4;
    int* part     = (int*)(ws + off);   off += 512;
    int* partoff  = (int*)(ws + off);   off += 512;
    short* hbf    = (short*)(ws + off); off += (size_t)NN * EMB * 2;   // 12.8 MB
    short* eproj  = (short*)(ws + off); off += (size_t)ECH * EMB * 2;  // 51.2 MB
    int* cnt      = cursor;  // alias: consumed by k_part before k_fix rewrites

    const int NB = (NN + 511) / 512;

    hipMemsetAsync(cnt, 0, (size_t)NN * sizeof(int), stream);
    k_proj_hist<<<NPROJ + NHIST, 256, 0, stream>>>(X, W, Wb, hbuf, hbf, rcv, cnt);
    k_part<<<NB, 512, 0, stream>>>(cnt, rowptr, part);
    k_scan2<<<1, 128, 0, stream>>>(part, partoff, rowptr);
    k_fix<<<NB, 512, 0, stream>>>(rowptr, partoff, cursor);
    k_bucket<<<NE / 256, 256, 0, stream>>>(snd, rcv, cursor, csr_snd, csr_pos);
    for (int e0 = 0; e0 < NE; e0 += ECH) {
        k_eproj<<<1024, 256, 0, stream>>>(EF + (size_t)e0 * ED, We, eproj, ECH);
        k_logit<<<2048, 256, 0, stream>>>(eproj, Web, Av, hbf, snd, rcv,
                                          csr_pos, ex_csr, e0, ECH);
    }
    k_agg<<<(NN + 3) / 4, 256, 0, stream>>>(hbuf, csr_snd, ex_csr, rowptr, out);
}

// Round 8
// 379.983 us; speedup vs baseline: 1.2655x; 1.2655x over previous
//
#include <hip/hip_runtime.h>
#include <math.h>

#define NN 50000
#define NE 800000
#define IND 256
#define ED 64
#define EMB 128
#define NH 8
#define HD 16

typedef short bf16x8 __attribute__((ext_vector_type(8)));
typedef float f32x4 __attribute__((ext_vector_type(4)));

#define NPROJ ((NN + 31) / 32)
#define NHIST ((NE + 255) / 256)

__device__ __forceinline__ unsigned short rne16(float f) {
    unsigned u = __float_as_uint(f);
    unsigned r = u + 0x7FFFu + ((u >> 16) & 1u);
    return (unsigned short)(r >> 16);
}

__device__ __forceinline__ float bf2f(short s) {
    return __uint_as_float(((unsigned)(unsigned short)s) << 16);
}

__device__ __forceinline__ float mishf(float v) {
    float t = __expf(fminf(v, 20.f));
    float u = 1.f + t;
    u = u * u;
    return v * (u - 1.f) * __builtin_amdgcn_rcpf(u + 1.f);
}

// ------- fused: node projection (blocks < NPROJ) + rcv histogram -----------
__global__ __launch_bounds__(256) void k_proj_hist(
    const float* __restrict__ X, const float* __restrict__ W,
    const float* __restrict__ b, short* __restrict__ hbf,
    const int* __restrict__ rcv, int* __restrict__ cnt) {
    if (blockIdx.x >= NPROJ) {
        int e = (blockIdx.x - NPROJ) * 256 + threadIdx.x;
        if (e < NE) atomicAdd(&cnt[rcv[e]], 1);
        return;
    }
    __shared__ float As[32][32];
    __shared__ float Ws[32][128];
    const int row0 = blockIdx.x * 32;
    const int tid = threadIdx.x;
    const int col = (tid & 31) * 4;
    const int rb  = (tid >> 5) * 4;
    float acc[4][4] = {};
    for (int k0 = 0; k0 < IND; k0 += 32) {
        {
            int r = tid >> 5, kk = tid & 31;
            #pragma unroll
            for (int i = 0; i < 4; ++i) {
                int rr = r + i * 8;
                int gr = row0 + rr;
                As[rr][kk] = (gr < NN) ? X[(size_t)gr * IND + k0 + kk] : 0.f;
            }
        }
        {
            int j = tid & 127, kb = tid >> 7;
            #pragma unroll
            for (int i = 0; i < 16; ++i) {
                int kk = kb + i * 2;
                Ws[kk][j] = W[(size_t)(k0 + kk) * EMB + j];
            }
        }
        __syncthreads();
        #pragma unroll
        for (int kk = 0; kk < 32; ++kk) {
            float4 wv = *(const float4*)&Ws[kk][col];
            float av[4];
            #pragma unroll
            for (int r = 0; r < 4; ++r) av[r] = As[rb + r][kk];
            #pragma unroll
            for (int r = 0; r < 4; ++r) {
                acc[r][0] = fmaf(av[r], wv.x, acc[r][0]);
                acc[r][1] = fmaf(av[r], wv.y, acc[r][1]);
                acc[r][2] = fmaf(av[r], wv.z, acc[r][2]);
                acc[r][3] = fmaf(av[r], wv.w, acc[r][3]);
            }
        }
        __syncthreads();
    }
    #pragma unroll
    for (int r = 0; r < 4; ++r) {
        int gr = row0 + rb + r;
        if (gr < NN) {
            short4 hb;
            hb.x = (short)rne16(acc[r][0] + b[col]);
            hb.y = (short)rne16(acc[r][1] + b[col + 1]);
            hb.z = (short)rne16(acc[r][2] + b[col + 2]);
            hb.w = (short)rne16(acc[r][3] + b[col + 3]);
            *(short4*)&hbf[(size_t)gr * EMB + col] = hb;
        }
    }
}

// ---------------- CSR build ------------------------------------------------
__global__ __launch_bounds__(512) void k_part(const int* __restrict__ cnt,
                                              int* __restrict__ rowptr,
                                              int* __restrict__ part) {
    __shared__ int sm[512];
    const int t = threadIdx.x;
    const int idx = blockIdx.x * 512 + t;
    int v = (idx < NN) ? cnt[idx] : 0;
    sm[t] = v;
    __syncthreads();
    #pragma unroll
    for (int off = 1; off < 512; off <<= 1) {
        int y = (t >= off) ? sm[t - off] : 0;
        __syncthreads();
        sm[t] += y;
        __syncthreads();
    }
    if (idx < NN) rowptr[idx] = sm[t] - v;
    if (t == 511) part[blockIdx.x] = sm[511];
}

__global__ __launch_bounds__(128) void k_scan2(const int* __restrict__ part,
                                               int* __restrict__ partoff,
                                               int* __restrict__ rowptr) {
    __shared__ int sm[128];
    const int t = threadIdx.x;
    const int NB = (NN + 511) / 512;
    int v = (t < NB) ? part[t] : 0;
    sm[t] = v;
    __syncthreads();
    #pragma unroll
    for (int off = 1; off < 128; off <<= 1) {
        int y = (t >= off) ? sm[t - off] : 0;
        __syncthreads();
        sm[t] += y;
        __syncthreads();
    }
    if (t < NB) partoff[t] = sm[t] - v;
    if (t == 0) rowptr[NN] = NE;
}

__global__ __launch_bounds__(512) void k_fix(int* __restrict__ rowptr,
                                             const int* __restrict__ partoff,
                                             int* __restrict__ cursor) {
    const int idx = blockIdx.x * 512 + threadIdx.x;
    if (idx < NN) {
        int r = rowptr[idx] + partoff[blockIdx.x];
        rowptr[idx] = r;
        cursor[idx] = r;
    }
}

__global__ __launch_bounds__(256) void k_bucket(
    const int* __restrict__ snd, const int* __restrict__ rcv,
    int* __restrict__ cursor, int* __restrict__ csr_snd,
    int* __restrict__ csr_pos) {
    int e = blockIdx.x * 256 + threadIdx.x;
    if (e < NE) {
        int pos = atomicAdd(&cursor[rcv[e]], 1);
        csr_snd[pos] = snd[e];
        csr_pos[e] = pos;
    }
}

// ---------- fused edge pass: plain-bf16 MFMA + gather + mish + exp ---------
// chunk c, lane j -> EMB col j*8+c (lane owns 8 consecutive cols).
__global__ __launch_bounds__(256) void k_edge_attn(
    const float* __restrict__ EF, const float* __restrict__ We,
    const float* __restrict__ Web, const float* __restrict__ Av,
    const short* __restrict__ hbf, const int* __restrict__ snd,
    const int* __restrict__ rcv, const int* __restrict__ csr_pos,
    float* __restrict__ ex_csr) {
    __shared__ bf16x8 BH[1024];    // 16 KB
    for (int t = threadIdx.x; t < 1024; t += 256) {
        int ckk = t >> 6;
        int lane = t & 63;
        int c = ckk >> 1;
        int colg = (lane & 15) * 8 + c;            // permuted column
        int kb = (ckk & 1) * 32 + (lane >> 4) * 8;
        bf16x8 vh;
        #pragma unroll
        for (int j = 0; j < 8; ++j)
            vh[j] = (short)rne16(We[(size_t)(kb + j) * EMB + colg]);
        BH[t] = vh;
    }
    __syncthreads();

    const int l = threadIdx.x & 63;
    const int lanecol = l & 15;
    const int q = l >> 4;
    const int wid = (blockIdx.x << 2) + (threadIdx.x >> 6);
    const int nW = gridDim.x << 2;

    float4 wbv0 = *(const float4*)&Web[lanecol * 8];
    float4 wbv1 = *(const float4*)&Web[lanecol * 8 + 4];
    float4 avv0 = *(const float4*)&Av[lanecol * 8];
    float4 avv1 = *(const float4*)&Av[lanecol * 8 + 4];
    float web[8] = {wbv0.x, wbv0.y, wbv0.z, wbv0.w, wbv1.x, wbv1.y, wbv1.z, wbv1.w};
    float av[8]  = {avv0.x, avv0.y, avv0.z, avv0.w, avv1.x, avv1.y, avv1.z, avv1.w};

    const int NT = NE / 16;
    for (int tIdx = wid; tIdx < NT; tIdx += nW) {
        const int e0 = tIdx * 16;
        const float* ar = EF + (size_t)(e0 + lanecol) * ED + q * 8;
        float fa[16];
        *(float4*)&fa[0]  = *(const float4*)ar;
        *(float4*)&fa[4]  = *(const float4*)(ar + 4);
        *(float4*)&fa[8]  = *(const float4*)(ar + 32);
        *(float4*)&fa[12] = *(const float4*)(ar + 36);
        bf16x8 ahi[2];
        #pragma unroll
        for (int kk = 0; kk < 2; ++kk)
            #pragma unroll
            for (int j = 0; j < 8; ++j)
                ahi[kk][j] = (short)rne16(fa[kk * 8 + j]);
        f32x4 acc[8];
        #pragma unroll
        for (int c = 0; c < 8; ++c) acc[c] = (f32x4){0.f, 0.f, 0.f, 0.f};
        #pragma unroll
        for (int c = 0; c < 8; ++c) {
            #pragma unroll
            for (int kk = 0; kk < 2; ++kk) {
                bf16x8 bh = BH[(c * 2 + kk) * 64 + l];
                acc[c] = __builtin_amdgcn_mfma_f32_16x16x32_bf16(ahi[kk], bh, acc[c], 0, 0, 0);
            }
        }
        #pragma unroll
        for (int r = 0; r < 4; ++r) {
            const int e = e0 + (q << 2) + r;
            const int s = snd[e], rn = rcv[e];
            bf16x8 hsv8 = *(const bf16x8*)(hbf + (size_t)s * EMB + lanecol * 8);
            bf16x8 hrv8 = *(const bf16x8*)(hbf + (size_t)rn * EMB + lanecol * 8);
            float pp = 0.f;
            #pragma unroll
            for (int c = 0; c < 8; ++c) {
                float v = acc[c][r] + web[c] + bf2f(hsv8[c]) + bf2f(hrv8[c]);
                pp = fmaf(mishf(v), av[c], pp);
            }
            pp += __shfl_xor(pp, 1, 16);
            if ((lanecol & 1) == 0) {
                const int pos = csr_pos[e];
                ex_csr[(size_t)pos * NH + (lanecol >> 1)] = __expf(pp);
            }
        }
    }
}

// --------- segmented aggregation: bf16 h, lane owns cols 2l,2l+1 -----------
__global__ __launch_bounds__(256) void k_agg(
    const short* __restrict__ hbf, const int* __restrict__ csr_snd,
    const float* __restrict__ ex_csr, const int* __restrict__ rowptr,
    float* __restrict__ out) {
    const int l = threadIdx.x & 63;
    const int node = blockIdx.x * 4 + (threadIdx.x >> 6);
    if (node >= NN) return;
    const int beg = rowptr[node], end = rowptr[node + 1];
    const int h = l >> 3;               // head of cols 2l, 2l+1
    float a0 = 0.f, a1 = 0.f, den = 0.f;
    int j = beg;
    for (; j + 4 <= end; j += 4) {
        int s[4];
        float ex[4];
        unsigned hv[4];
        #pragma unroll
        for (int i = 0; i < 4; ++i) s[i] = csr_snd[j + i];
        #pragma unroll
        for (int i = 0; i < 4; ++i) ex[i] = ex_csr[(size_t)(j + i) * NH + h];
        #pragma unroll
        for (int i = 0; i < 4; ++i)
            hv[i] = *(const unsigned*)(hbf + (size_t)s[i] * EMB + 2 * l);
        #pragma unroll
        for (int i = 0; i < 4; ++i) {
            a0 = fmaf(ex[i], bf2f((short)(hv[i] & 0xFFFF)), a0);
            a1 = fmaf(ex[i], bf2f((short)(hv[i] >> 16)), a1);
            den += ex[i];
        }
    }
    for (; j < end; ++j) {
        float ex = ex_csr[(size_t)j * NH + h];
        unsigned hv = *(const unsigned*)(hbf + (size_t)csr_snd[j] * EMB + 2 * l);
        a0 = fmaf(ex, bf2f((short)(hv & 0xFFFF)), a0);
        a1 = fmaf(ex, bf2f((short)(hv >> 16)), a1);
        den += ex;
    }
    float rd = (end > beg) ? __builtin_amdgcn_rcpf(den) : 0.f;
    float2 o;
    o.x = a0 * rd;
    o.y = a1 * rd;
    *(float2*)&out[(size_t)node * EMB + 2 * l] = o;
}

extern "C" void kernel_launch(void* const* d_in, const int* in_sizes, int n_in,
                              void* d_out, int out_size, void* d_ws, size_t ws_size,
                              hipStream_t stream) {
    const float* X   = (const float*)d_in[0];
    const float* EF  = (const float*)d_in[1];
    const float* W   = (const float*)d_in[2];
    const float* Wb  = (const float*)d_in[3];
    const float* We  = (const float*)d_in[4];
    const float* Web = (const float*)d_in[5];
    const float* Av  = (const float*)d_in[6];
    const int* snd   = (const int*)d_in[7];
    const int* rcv   = (const int*)d_in[8];
    float* out = (float*)d_out;

    char* ws = (char*)d_ws;
    size_t off = 0;
    float* ex_csr = (float*)(ws + off); off += (size_t)NE * NH * 4;    // 25.6 MB
    int* csr_snd  = (int*)(ws + off);   off += (size_t)NE * 4;         // 3.2 MB
    int* csr_pos  = (int*)(ws + off);   off += (size_t)NE * 4;         // 3.2 MB
    int* rowptr   = (int*)(ws + off);   off += (size_t)(NN + 1) * 4;
    int* cursor   = (int*)(ws + off);   off += (size_t)NN * 4;
    int* part     = (int*)(ws + off);   off += 512;
    int* partoff  = (int*)(ws + off);   off += 512;
    short* hbf    = (short*)(ws + off); off += (size_t)NN * EMB * 2;   // 12.8 MB
    int* cnt      = cursor;  // alias: consumed by k_part before k_fix rewrites

    const int NB = (NN + 511) / 512;

    hipMemsetAsync(cnt, 0, (size_t)NN * sizeof(int), stream);
    k_proj_hist<<<NPROJ + NHIST, 256, 0, stream>>>(X, W, Wb, hbf, rcv, cnt);
    k_part<<<NB, 512, 0, stream>>>(cnt, rowptr, part);
    k_scan2<<<1, 128, 0, stream>>>(part, partoff, rowptr);
    k_fix<<<NB, 512, 0, stream>>>(rowptr, partoff, cursor);
    k_bucket<<<NE / 256, 256, 0, stream>>>(snd, rcv, cursor, csr_snd, csr_pos);
    k_edge_attn<<<2560, 256, 0, stream>>>(EF, We, Web, Av, hbf, snd, rcv, csr_pos, ex_csr);
    k_agg<<<(NN + 3) / 4, 256, 0, stream>>>(hbf, csr_snd, ex_csr, rowptr, out);
}

// Round 9
// 312.899 us; speedup vs baseline: 1.5369x; 1.2144x over previous
//
#include <hip/hip_runtime.h>
#include <math.h>

#define NN 50000
#define NE 800000
#define IND 256
#define ED 64
#define EMB 128
#define NH 8
#define HD 16

typedef short bf16x8 __attribute__((ext_vector_type(8)));
typedef float f32x4 __attribute__((ext_vector_type(4)));

#define NPT  (NN / 16)                  // 3125 proj tiles (50000 = 16*3125)
#define NPB  ((NPT + 3) / 4)            // 782 proj blocks (4 waves each)
#define NHIST ((NE + 255) / 256)        // 3125 hist blocks
#define NB   ((NN + 511) / 512)         // 98 scan blocks

__device__ __forceinline__ unsigned short rne16(float f) {
    unsigned u = __float_as_uint(f);
    unsigned r = u + 0x7FFFu + ((u >> 16) & 1u);
    return (unsigned short)(r >> 16);
}

__device__ __forceinline__ float bf2f(short s) {
    return __uint_as_float(((unsigned)(unsigned short)s) << 16);
}

__device__ __forceinline__ float mishf(float v) {
    float t = __expf(fminf(v, 20.f));
    float u = 1.f + t;
    u = u * u;
    return v * (u - 1.f) * __builtin_amdgcn_rcpf(u + 1.f);
}

// ------- fused: MFMA node projection + rcv histogram -----------------------
// W staged once as bf16 fragments (64 KB LDS), permuted cols (lane j owns
// cols j*8..j*8+7). Wave = 16 nodes, K=256 in 8 chunks, 64 MFMA/tile.
__global__ __launch_bounds__(256) void k_proj_hist(
    const float* __restrict__ X, const float* __restrict__ W,
    const float* __restrict__ b, short* __restrict__ hbf,
    const int* __restrict__ rcv, int* __restrict__ cnt) {
    if (blockIdx.x >= NPB) {            // histogram part
        int e = (blockIdx.x - NPB) * 256 + threadIdx.x;
        if (e < NE) atomicAdd(&cnt[rcv[e]], 1);
        return;
    }
    __shared__ short BHs[IND * EMB];    // 64 KB bf16 fragment tile
    for (int idx = threadIdx.x * 4; idx < IND * EMB; idx += 256 * 4) {
        float4 wv = *(const float4*)&W[idx];   // coalesced read
        int k = idx >> 7;
        int col = idx & 127;
        int kk8 = k >> 5, qq = (k & 31) >> 3, j = k & 7;
        float wf[4] = {wv.x, wv.y, wv.z, wv.w};
        #pragma unroll
        for (int i = 0; i < 4; ++i) {
            int cc = (col + i) & 7, lc = (col + i) >> 3;
            int lane = (qq << 4) | lc;
            BHs[(((cc << 3) | kk8) * 64 + lane) * 8 + j] = (short)rne16(wf[i]);
        }
    }
    __syncthreads();

    const int l = threadIdx.x & 63;
    const int lanecol = l & 15;
    const int q = l >> 4;
    const int wid = (blockIdx.x << 2) + (threadIdx.x >> 6);
    const int nW = NPB << 2;

    float4 bv0 = *(const float4*)&b[lanecol * 8];
    float4 bv1 = *(const float4*)&b[lanecol * 8 + 4];
    float wb[8] = {bv0.x, bv0.y, bv0.z, bv0.w, bv1.x, bv1.y, bv1.z, bv1.w};

    for (int tIdx = wid; tIdx < NPT; tIdx += nW) {
        const int n0 = tIdx * 16;
        f32x4 acc[8];
        #pragma unroll
        for (int c = 0; c < 8; ++c) acc[c] = (f32x4){0.f, 0.f, 0.f, 0.f};
        #pragma unroll
        for (int kk8 = 0; kk8 < 8; ++kk8) {
            const float* ar = X + (size_t)(n0 + lanecol) * IND + kk8 * 32 + q * 8;
            float4 a0 = *(const float4*)ar;
            float4 a1 = *(const float4*)(ar + 4);
            float faf[8] = {a0.x, a0.y, a0.z, a0.w, a1.x, a1.y, a1.z, a1.w};
            bf16x8 ahi;
            #pragma unroll
            for (int j = 0; j < 8; ++j) ahi[j] = (short)rne16(faf[j]);
            #pragma unroll
            for (int c = 0; c < 8; ++c) {
                bf16x8 bh = *(bf16x8*)&BHs[(((c << 3) | kk8) * 64 + l) * 8];
                acc[c] = __builtin_amdgcn_mfma_f32_16x16x32_bf16(ahi, bh, acc[c], 0, 0, 0);
            }
        }
        #pragma unroll
        for (int r = 0; r < 4; ++r) {
            const int node = n0 + (q << 2) + r;
            bf16x8 ov;
            #pragma unroll
            for (int c = 0; c < 8; ++c) ov[c] = (short)rne16(acc[c][r] + wb[c]);
            *(bf16x8*)(hbf + (size_t)node * EMB + lanecol * 8) = ov;
        }
    }
}

// ---------------- CSR build: per-block scan, merged fixup ------------------
__global__ __launch_bounds__(512) void k_part(const int* __restrict__ cnt,
                                              int* __restrict__ rowptr,
                                              int* __restrict__ part) {
    __shared__ int sm[512];
    const int t = threadIdx.x;
    const int idx = blockIdx.x * 512 + t;
    int v = (idx < NN) ? cnt[idx] : 0;
    sm[t] = v;
    __syncthreads();
    #pragma unroll
    for (int off = 1; off < 512; off <<= 1) {
        int y = (t >= off) ? sm[t - off] : 0;
        __syncthreads();
        sm[t] += y;
        __syncthreads();
    }
    if (idx < NN) rowptr[idx] = sm[t] - v;
    if (t == 511) part[blockIdx.x] = sm[511];
}

// every block redundantly scans the 98 partials, then fixes its slice
__global__ __launch_bounds__(512) void k_fix2(const int* __restrict__ part,
                                              int* __restrict__ rowptr,
                                              int* __restrict__ cursor) {
    __shared__ int sm[128];
    const int t = threadIdx.x;
    if (t < 128) sm[t] = (t < NB) ? part[t] : 0;
    __syncthreads();
    #pragma unroll
    for (int off = 1; off < 128; off <<= 1) {
        int y = 0;
        if (t < 128 && t >= off) y = sm[t - off];
        __syncthreads();
        if (t < 128) sm[t] += y;
        __syncthreads();
    }
    const int boff = (blockIdx.x > 0) ? sm[blockIdx.x - 1] : 0;
    const int idx = blockIdx.x * 512 + t;
    if (idx < NN) {
        int r = rowptr[idx] + boff;
        rowptr[idx] = r;
        cursor[idx] = r;
    }
    if (blockIdx.x == 0 && t == 0) rowptr[NN] = NE;
}

// ---------- fused edge pass: bf16 MFMA + gather + mish + exp + bucket ------
__global__ __launch_bounds__(256) void k_edge_attn(
    const float* __restrict__ EF, const float* __restrict__ We,
    const float* __restrict__ Web, const float* __restrict__ Av,
    const short* __restrict__ hbf, const int* __restrict__ snd,
    const int* __restrict__ rcv, int* __restrict__ cursor,
    int* __restrict__ csr_snd, float* __restrict__ ex_csr) {
    __shared__ short BHs[ED * EMB];     // 16 KB bf16 fragment tile
    for (int idx = threadIdx.x * 4; idx < ED * EMB; idx += 256 * 4) {
        float4 wv = *(const float4*)&We[idx];
        int k = idx >> 7;
        int col = idx & 127;
        int kk = k >> 5, qq = (k & 31) >> 3, j = k & 7;
        float wf[4] = {wv.x, wv.y, wv.z, wv.w};
        #pragma unroll
        for (int i = 0; i < 4; ++i) {
            int cc = (col + i) & 7, lc = (col + i) >> 3;
            int lane = (qq << 4) | lc;
            BHs[(((cc << 1) | kk) * 64 + lane) * 8 + j] = (short)rne16(wf[i]);
        }
    }
    __syncthreads();

    const int l = threadIdx.x & 63;
    const int lanecol = l & 15;
    const int q = l >> 4;
    const int wid = (blockIdx.x << 2) + (threadIdx.x >> 6);
    const int nW = gridDim.x << 2;

    float4 wbv0 = *(const float4*)&Web[lanecol * 8];
    float4 wbv1 = *(const float4*)&Web[lanecol * 8 + 4];
    float4 avv0 = *(const float4*)&Av[lanecol * 8];
    float4 avv1 = *(const float4*)&Av[lanecol * 8 + 4];
    float web[8] = {wbv0.x, wbv0.y, wbv0.z, wbv0.w, wbv1.x, wbv1.y, wbv1.z, wbv1.w};
    float av[8]  = {avv0.x, avv0.y, avv0.z, avv0.w, avv1.x, avv1.y, avv1.z, avv1.w};

    const int NT = NE / 16;
    for (int tIdx = wid; tIdx < NT; tIdx += nW) {
        const int e0 = tIdx * 16;
        const float* ar = EF + (size_t)(e0 + lanecol) * ED + q * 8;
        float fa[16];
        *(float4*)&fa[0]  = *(const float4*)ar;
        *(float4*)&fa[4]  = *(const float4*)(ar + 4);
        *(float4*)&fa[8]  = *(const float4*)(ar + 32);
        *(float4*)&fa[12] = *(const float4*)(ar + 36);
        bf16x8 ahi[2];
        #pragma unroll
        for (int kk = 0; kk < 2; ++kk)
            #pragma unroll
            for (int j = 0; j < 8; ++j)
                ahi[kk][j] = (short)rne16(fa[kk * 8 + j]);
        f32x4 acc[8];
        #pragma unroll
        for (int c = 0; c < 8; ++c) acc[c] = (f32x4){0.f, 0.f, 0.f, 0.f};
        #pragma unroll
        for (int c = 0; c < 8; ++c) {
            #pragma unroll
            for (int kk = 0; kk < 2; ++kk) {
                bf16x8 bh = *(bf16x8*)&BHs[(((c << 1) | kk) * 64 + l) * 8];
                acc[c] = __builtin_amdgcn_mfma_f32_16x16x32_bf16(ahi[kk], bh, acc[c], 0, 0, 0);
            }
        }
        #pragma unroll
        for (int r = 0; r < 4; ++r) {
            const int e = e0 + (q << 2) + r;
            const int s = snd[e], rn = rcv[e];
            bf16x8 hsv8 = *(const bf16x8*)(hbf + (size_t)s * EMB + lanecol * 8);
            bf16x8 hrv8 = *(const bf16x8*)(hbf + (size_t)rn * EMB + lanecol * 8);
            float pp = 0.f;
            #pragma unroll
            for (int c = 0; c < 8; ++c) {
                float v = acc[c][r] + web[c] + bf2f(hsv8[c]) + bf2f(hrv8[c]);
                pp = fmaf(mishf(v), av[c], pp);
            }
            pp += __shfl_xor(pp, 1, 16);
            // fused bucket: one atomic per edge, broadcast slot to group
            int pos = 0;
            if (lanecol == 0) pos = atomicAdd(&cursor[rn], 1);
            pos = __shfl(pos, l & 48, 64);
            if (lanecol == 0) csr_snd[pos] = s;
            if ((lanecol & 1) == 0)
                ex_csr[(size_t)pos * NH + (lanecol >> 1)] = __expf(pp);
        }
    }
}

// --------- segmented aggregation: bf16 h, lane owns cols 2l,2l+1 -----------
__global__ __launch_bounds__(256) void k_agg(
    const short* __restrict__ hbf, const int* __restrict__ csr_snd,
    const float* __restrict__ ex_csr, const int* __restrict__ rowptr,
    float* __restrict__ out) {
    const int l = threadIdx.x & 63;
    const int node = blockIdx.x * 4 + (threadIdx.x >> 6);
    if (node >= NN) return;
    const int beg = rowptr[node], end = rowptr[node + 1];
    const int h = l >> 3;
    float a0 = 0.f, a1 = 0.f, den = 0.f;
    int j = beg;
    for (; j + 4 <= end; j += 4) {
        int s[4];
        float ex[4];
        unsigned hv[4];
        #pragma unroll
        for (int i = 0; i < 4; ++i) s[i] = csr_snd[j + i];
        #pragma unroll
        for (int i = 0; i < 4; ++i) ex[i] = ex_csr[(size_t)(j + i) * NH + h];
        #pragma unroll
        for (int i = 0; i < 4; ++i)
            hv[i] = *(const unsigned*)(hbf + (size_t)s[i] * EMB + 2 * l);
        #pragma unroll
        for (int i = 0; i < 4; ++i) {
            a0 = fmaf(ex[i], bf2f((short)(hv[i] & 0xFFFF)), a0);
            a1 = fmaf(ex[i], bf2f((short)(hv[i] >> 16)), a1);
            den += ex[i];
        }
    }
    for (; j < end; ++j) {
        float ex = ex_csr[(size_t)j * NH + h];
        unsigned hv = *(const unsigned*)(hbf + (size_t)csr_snd[j] * EMB + 2 * l);
        a0 = fmaf(ex, bf2f((short)(hv & 0xFFFF)), a0);
        a1 = fmaf(ex, bf2f((short)(hv >> 16)), a1);
        den += ex;
    }
    float rd = (end > beg) ? __builtin_amdgcn_rcpf(den) : 0.f;
    float2 o;
    o.x = a0 * rd;
    o.y = a1 * rd;
    *(float2*)&out[(size_t)node * EMB + 2 * l] = o;
}

extern "C" void kernel_launch(void* const* d_in, const int* in_sizes, int n_in,
                              void* d_out, int out_size, void* d_ws, size_t ws_size,
                              hipStream_t stream) {
    const float* X   = (const float*)d_in[0];
    const float* EF  = (const float*)d_in[1];
    const float* W   = (const float*)d_in[2];
    const float* Wb  = (const float*)d_in[3];
    const float* We  = (const float*)d_in[4];
    const float* Web = (const float*)d_in[5];
    const float* Av  = (const float*)d_in[6];
    const int* snd   = (const int*)d_in[7];
    const int* rcv   = (const int*)d_in[8];
    float* out = (float*)d_out;

    char* ws = (char*)d_ws;
    size_t off = 0;
    float* ex_csr = (float*)(ws + off); off += (size_t)NE * NH * 4;    // 25.6 MB
    int* csr_snd  = (int*)(ws + off);   off += (size_t)NE * 4;         // 3.2 MB
    int* rowptr   = (int*)(ws + off);   off += (size_t)(NN + 1) * 4;
    int* cursor   = (int*)(ws + off);   off += (size_t)NN * 4;
    int* part     = (int*)(ws + off);   off += 512;
    short* hbf    = (short*)(ws + off); off += (size_t)NN * EMB * 2;   // 12.8 MB
    int* cnt      = cursor;  // alias: consumed by k_part before k_fix2 rewrites

    hipMemsetAsync(cnt, 0, (size_t)NN * sizeof(int), stream);
    k_proj_hist<<<NPB + NHIST, 256, 0, stream>>>(X, W, Wb, hbf, rcv, cnt);
    k_part<<<NB, 512, 0, stream>>>(cnt, rowptr, part);
    k_fix2<<<NB, 512, 0, stream>>>(part, rowptr, cursor);
    k_edge_attn<<<2560, 256, 0, stream>>>(EF, We, Web, Av, hbf, snd, rcv,
                                          cursor, csr_snd, ex_csr);
    k_agg<<<(NN + 3) / 4, 256, 0, stream>>>(hbf, csr_snd, ex_csr, rowptr, out);
}